// Round 1
// baseline (98.505 us; speedup 1.0000x reference)
//
#include <hip/hip_runtime.h>
#include <stdint.h>

#define NN 200000
#define DEG 32
#define BB 16384
#define DD 128
#define HH 128

struct Keys { unsigned a[5][2]; unsigned l[5][2]; };

__host__ __device__ __forceinline__ unsigned rotl32(unsigned v, int r) {
  return (v << r) | (v >> (32 - r));
}

// JAX threefry2x32 (Random123), 20 rounds. First counter word pairs with ks0.
__host__ __device__ __forceinline__ void threefry2x32(
    unsigned k0, unsigned k1, unsigned x0, unsigned x1,
    unsigned* o0, unsigned* o1) {
  unsigned ks0 = k0, ks1 = k1, ks2 = k0 ^ k1 ^ 0x1BD11BDAu;
  x0 += ks0; x1 += ks1;
#define TF_RND(r) { x0 += x1; x1 = rotl32(x1, (r)); x1 ^= x0; }
  TF_RND(13) TF_RND(15) TF_RND(26) TF_RND(6)
  x0 += ks1; x1 += ks2 + 1u;
  TF_RND(17) TF_RND(29) TF_RND(16) TF_RND(24)
  x0 += ks2; x1 += ks0 + 2u;
  TF_RND(13) TF_RND(15) TF_RND(26) TF_RND(6)
  x0 += ks0; x1 += ks1 + 3u;
  TF_RND(17) TF_RND(29) TF_RND(16) TF_RND(24)
  x0 += ks1; x1 += ks2 + 4u;
  TF_RND(13) TF_RND(15) TF_RND(26) TF_RND(6)
  x0 += ks2; x1 += ks0 + 5u;
#undef TF_RND
  *o0 = x0; *o1 = x1;
}

// One 32-lane group per (walk, row). 5 sequential weighted-categorical steps.
__global__ __launch_bounds__(256) void walk_kernel(
    const int* __restrict__ neighbors, const float* __restrict__ ew,
    const int* __restrict__ target, int* __restrict__ walks, Keys keys) {
  int lane = threadIdx.x & 63;
  int sub = lane & 31;                      // degree slot
  int grp = (int)((blockIdx.x * 256 + threadIdx.x) >> 5);  // [0, 2*BB)
  int wk = grp >= BB ? 1 : 0;
  int b = grp - wk * BB;

  int cur = target[b];
  if (sub == 0) walks[(size_t)grp * 6] = cur;

  const float TINY = 1.17549435e-38f;       // np.finfo(float32).tiny

  for (int s = 0; s < 5; ++s) {
    int nb = neighbors[(size_t)cur * DEG + sub];
    float w = ew[(size_t)cur * DEG + sub];

    // partitionable threefry random_bits: counter = 64-bit flat index (hi=0)
    unsigned j = (unsigned)b * DEG + (unsigned)sub;
    unsigned k0 = wk ? keys.l[s][0] : keys.a[s][0];
    unsigned k1 = wk ? keys.l[s][1] : keys.a[s][1];
    unsigned y0, y1;
    threefry2x32(k0, k1, 0u, j, &y0, &y1);
    unsigned bits = y0 ^ y1;                // 32-bit fold

    // jax.random.uniform(minval=tiny, maxval=1.0)
    float f = __uint_as_float((bits >> 9) | 0x3f800000u) - 1.0f;
    float u = fmaxf(TINY, f + TINY);        // f*(1-tiny)+tiny == f+tiny in fp32
    // gumbel + logits
    float g = -logf(-logf(u));
    float v = g + logf(w);

    // 32-lane argmax, first index wins on exact tie (jnp.argmax semantics)
    int idx = sub;
    #pragma unroll
    for (int off = 16; off; off >>= 1) {
      float vo = __shfl_xor(v, off);
      int io = __shfl_xor(idx, off);
      if (vo > v || (vo == v && io < idx)) { v = vo; idx = io; }
    }
    cur = __shfl(nb, (lane & 32) + idx);
    if (sub == 0) walks[(size_t)grp * 6 + s + 1] = cur;
  }
}

// 4 rows per 128-thread block: gather + 2x (256x128) matvec + 3-way attention.
#define ROWS 4
__global__ __launch_bounds__(128) void fuse_kernel(
    const float* __restrict__ x_app, const float* __restrict__ x_loc,
    const float* __restrict__ x_time, const int* __restrict__ target,
    const int* __restrict__ walks,
    const float* __restrict__ W_app, const float* __restrict__ b_app,
    const float* __restrict__ W_loc, const float* __restrict__ b_loc,
    const float* __restrict__ W_att, const float* __restrict__ b_att,
    float* __restrict__ out) {
  int h = threadIdx.x;                      // 0..127
  int b0 = blockIdx.x * ROWS;

  __shared__ float sA[ROWS][256];
  __shared__ float sL[ROWS][256];
  float ttime[ROWS];

  for (int r = 0; r < ROWS; ++r) {
    int b = b0 + r;
    int t = target[b];
    const int* aw = walks + (size_t)b * 6;
    const int* lw = walks + (size_t)(BB + b) * 6;
    float sa = 0.f, sl = 0.f;
    #pragma unroll
    for (int i = 0; i < 6; ++i) {
      sa += x_app[(size_t)aw[i] * DD + h];
      sl += x_loc[(size_t)lw[i] * DD + h];
    }
    sA[r][h] = x_app[(size_t)t * DD + h];
    sA[r][128 + h] = sa;
    sL[r][h] = x_loc[(size_t)t * DD + h];
    sL[r][128 + h] = sl;
    ttime[r] = x_time[(size_t)t * HH + h];
  }
  __syncthreads();

  float accA[ROWS], accL[ROWS];
  float ba = b_app[h], bl = b_loc[h];
  #pragma unroll
  for (int r = 0; r < ROWS; ++r) { accA[r] = ba; accL[r] = bl; }

  for (int i = 0; i < 256; ++i) {
    float wa = W_app[i * 128 + h];
    float wl = W_loc[i * 128 + h];
    #pragma unroll
    for (int r = 0; r < ROWS; ++r) {
      accA[r] = fmaf(sA[r][i], wa, accA[r]);
      accL[r] = fmaf(sL[r][i], wl, accL[r]);
    }
  }

  float watt_t = W_att[h];
  float watt_f = W_att[128 + h];
  float batt = b_att[0];
  int lane = threadIdx.x & 63;
  int wv = threadIdx.x >> 6;
  __shared__ float4 red[2];

  for (int r = 0; r < ROWS; ++r) {
    float fa = fmaxf(accA[r], 0.f);
    float fl = fmaxf(accL[r], 0.f);
    float tt = ttime[r];
    float ta = sA[r][h];
    float4 q;
    q.x = ta * watt_t;   // shared t_app · W_att[:128] part
    q.y = fa * watt_f;
    q.z = fl * watt_f;
    q.w = tt * watt_f;
    #pragma unroll
    for (int off = 32; off; off >>= 1) {
      q.x += __shfl_xor(q.x, off);
      q.y += __shfl_xor(q.y, off);
      q.z += __shfl_xor(q.z, off);
      q.w += __shfl_xor(q.w, off);
    }
    if (lane == 0) red[wv] = q;
    __syncthreads();
    float4 t0 = red[0], t1 = red[1];
    float pt = t0.x + t1.x;
    float s0 = pt + t0.y + t1.y + batt;
    float s1 = pt + t0.z + t1.z + batt;
    float s2 = pt + t0.w + t1.w + batt;
    float m = fmaxf(s0, fmaxf(s1, s2));
    float e0 = expf(s0 - m), e1 = expf(s1 - m), e2 = expf(s2 - m);
    float inv = 1.f / (e0 + e1 + e2);
    out[(size_t)(b0 + r) * HH + h] = (e0 * fa + e1 * fl + e2 * tt) * inv;
    __syncthreads();
  }
}

extern "C" void kernel_launch(void* const* d_in, const int* in_sizes, int n_in,
                              void* d_out, int out_size, void* d_ws, size_t ws_size,
                              hipStream_t stream) {
  (void)in_sizes; (void)n_in; (void)out_size; (void)ws_size;
  const float* x_app   = (const float*)d_in[0];
  const float* x_loc   = (const float*)d_in[1];
  const float* x_time  = (const float*)d_in[2];
  const int*   neighbors = (const int*)d_in[3];
  const float* ew      = (const float*)d_in[4];
  const int*   target  = (const int*)d_in[5];
  const float* W_app   = (const float*)d_in[6];
  const float* b_app   = (const float*)d_in[7];
  const float* W_loc   = (const float*)d_in[8];
  const float* b_loc   = (const float*)d_in[9];
  const float* W_att   = (const float*)d_in[10];
  const float* b_att   = (const float*)d_in[11];
  float* out = (float*)d_out;
  int* walks = (int*)d_ws;   // [2][BB][6] ints = 786 KB

  // Host-side key chain (partitionable / fold-like split):
  // kw = key(42) -> (0,42); k1,k2 = split(kw); step keys = split(k?, 5)
  Keys keys;
  unsigned k1a, k1b, k2a, k2b;
  threefry2x32(0u, 42u, 0u, 0u, &k1a, &k1b);
  threefry2x32(0u, 42u, 0u, 1u, &k2a, &k2b);
  for (unsigned s = 0; s < 5; ++s) {
    threefry2x32(k1a, k1b, 0u, s, &keys.a[s][0], &keys.a[s][1]);
    threefry2x32(k2a, k2b, 0u, s, &keys.l[s][0], &keys.l[s][1]);
  }

  walk_kernel<<<(2 * BB * 32) / 256, 256, 0, stream>>>(neighbors, ew, target, walks, keys);
  fuse_kernel<<<BB / ROWS, 128, 0, stream>>>(x_app, x_loc, x_time, target, walks,
                                             W_app, b_app, W_loc, b_loc, W_att, b_att, out);
}

// Round 2
// 64.864 us; speedup vs baseline: 1.5186x; 1.5186x over previous
//
#include <hip/hip_runtime.h>
#include <stdint.h>

#define NN 200000
#define DEG 32
#define BB 16384
#define DD 128
#define HH 128
#define BM 64

typedef __attribute__((ext_vector_type(8))) short bf16x8;
typedef __attribute__((ext_vector_type(4))) float f32x4;

struct Keys { unsigned a[5][2]; unsigned l[5][2]; };

__host__ __device__ __forceinline__ unsigned rotl32(unsigned v, int r) {
  return (v << r) | (v >> (32 - r));
}

__host__ __device__ __forceinline__ void threefry2x32(
    unsigned k0, unsigned k1, unsigned x0, unsigned x1,
    unsigned* o0, unsigned* o1) {
  unsigned ks0 = k0, ks1 = k1, ks2 = k0 ^ k1 ^ 0x1BD11BDAu;
  x0 += ks0; x1 += ks1;
#define TF_RND(r) { x0 += x1; x1 = rotl32(x1, (r)); x1 ^= x0; }
  TF_RND(13) TF_RND(15) TF_RND(26) TF_RND(6)
  x0 += ks1; x1 += ks2 + 1u;
  TF_RND(17) TF_RND(29) TF_RND(16) TF_RND(24)
  x0 += ks2; x1 += ks0 + 2u;
  TF_RND(13) TF_RND(15) TF_RND(26) TF_RND(6)
  x0 += ks0; x1 += ks1 + 3u;
  TF_RND(17) TF_RND(29) TF_RND(16) TF_RND(24)
  x0 += ks1; x1 += ks2 + 4u;
  TF_RND(13) TF_RND(15) TF_RND(26) TF_RND(6)
  x0 += ks2; x1 += ks0 + 5u;
#undef TF_RND
  *o0 = x0; *o1 = x1;
}

__device__ __forceinline__ unsigned short f2bf(float x) {
  unsigned u = __float_as_uint(x);
  unsigned r = (u + 0x7fffu + ((u >> 16) & 1u)) >> 16;
  return (unsigned short)r;
}

// ---------------- walk kernel (unchanged, verified) ----------------
__global__ __launch_bounds__(256) void walk_kernel(
    const int* __restrict__ neighbors, const float* __restrict__ ew,
    const int* __restrict__ target, int* __restrict__ walks, Keys keys) {
  int lane = threadIdx.x & 63;
  int sub = lane & 31;
  int grp = (int)((blockIdx.x * 256 + threadIdx.x) >> 5);
  int wk = grp >= BB ? 1 : 0;
  int b = grp - wk * BB;

  int cur = target[b];
  if (sub == 0) walks[(size_t)grp * 6] = cur;

  const float TINY = 1.17549435e-38f;

  for (int s = 0; s < 5; ++s) {
    int nb = neighbors[(size_t)cur * DEG + sub];
    float w = ew[(size_t)cur * DEG + sub];
    unsigned j = (unsigned)b * DEG + (unsigned)sub;
    unsigned k0 = wk ? keys.l[s][0] : keys.a[s][0];
    unsigned k1 = wk ? keys.l[s][1] : keys.a[s][1];
    unsigned y0, y1;
    threefry2x32(k0, k1, 0u, j, &y0, &y1);
    unsigned bits = y0 ^ y1;
    float f = __uint_as_float((bits >> 9) | 0x3f800000u) - 1.0f;
    float u = fmaxf(TINY, f + TINY);
    float g = -logf(-logf(u));
    float v = g + logf(w);
    int idx = sub;
    #pragma unroll
    for (int off = 16; off; off >>= 1) {
      float vo = __shfl_xor(v, off);
      int io = __shfl_xor(idx, off);
      if (vo > v || (vo == v && io < idx)) { v = vo; idx = io; }
    }
    cur = __shfl(nb, (lane & 32) + idx);
    if (sub == 0) walks[(size_t)grp * 6 + s + 1] = cur;
  }
}

// ---------------- W transpose+bf16 prep: Wt[2][128 n][256 k] ----------------
__global__ __launch_bounds__(256) void prep_w(
    const float* __restrict__ Wapp, const float* __restrict__ Wloc,
    unsigned short* __restrict__ Wt) {
  int blk = blockIdx.x;                 // 16 blocks: mat(2) x kchunk(8)
  int mat = blk >> 3;
  int k0 = (blk & 7) << 5;              // 32-k chunk
  const float* W = mat ? Wloc : Wapp;
  __shared__ float tile[32][129];
  int t = threadIdx.x;
  #pragma unroll
  for (int i = 0; i < 16; ++i) {
    int idx = t + (i << 8);
    int kk = idx >> 7, n = idx & 127;
    tile[kk][n] = W[((size_t)(k0 + kk) << 7) + n];
  }
  __syncthreads();
  int n = t >> 1, h = (t & 1) << 4;     // 16 k's per thread
  unsigned pk[8];
  #pragma unroll
  for (int j = 0; j < 8; ++j) {
    float lo = tile[h + 2 * j][n];
    float hi = tile[h + 2 * j + 1][n];
    pk[j] = (unsigned)f2bf(lo) | ((unsigned)f2bf(hi) << 16);
  }
  unsigned short* dst = Wt + ((size_t)mat << 15) + ((size_t)n << 8) + k0 + h;
  uint4 lo4; lo4.x = pk[0]; lo4.y = pk[1]; lo4.z = pk[2]; lo4.w = pk[3];
  uint4 hi4; hi4.x = pk[4]; hi4.y = pk[5]; hi4.z = pk[6]; hi4.w = pk[7];
  reinterpret_cast<uint4*>(dst)[0] = lo4;
  reinterpret_cast<uint4*>(dst)[1] = hi4;
}

// ---------------- fused gather + MFMA GEMM + attention ----------------
__global__ __launch_bounds__(256) void fuse2(
    const float* __restrict__ x_app, const float* __restrict__ x_loc,
    const float* __restrict__ x_time, const int* __restrict__ target,
    const int* __restrict__ walks, const unsigned short* __restrict__ Wt,
    const float* __restrict__ W_att, const float* __restrict__ b_att,
    const float* __restrict__ b_app, const float* __restrict__ b_loc,
    float* __restrict__ out) {
  __shared__ unsigned short sA[BM][264];   // [row][t(128) | sum(128)], pad 8
  __shared__ float attT[BM];

  int tid = threadIdx.x;
  int b0 = blockIdx.x * BM;
  int hw = tid >> 5;                       // half-wave 0..7
  int c = tid & 31;                        // covers cols 4c..4c+3

  // ---- gather app (+ t_app . W_att[:128]) ----
  #pragma unroll 2
  for (int it = 0; it < BM / 8; ++it) {
    int row = (it << 3) + hw;
    const int* wp = walks + (size_t)(b0 + row) * 6;
    int n0 = wp[0], n1 = wp[1], n2 = wp[2], n3 = wp[3], n4 = wp[4], n5 = wp[5];
    const float4 v0 = *(const float4*)&x_app[((size_t)n0 << 7) + 4 * c];
    const float4 v1 = *(const float4*)&x_app[((size_t)n1 << 7) + 4 * c];
    const float4 v2 = *(const float4*)&x_app[((size_t)n2 << 7) + 4 * c];
    const float4 v3 = *(const float4*)&x_app[((size_t)n3 << 7) + 4 * c];
    const float4 v4 = *(const float4*)&x_app[((size_t)n4 << 7) + 4 * c];
    const float4 v5 = *(const float4*)&x_app[((size_t)n5 << 7) + 4 * c];
    float sx = v0.x + v1.x + v2.x + v3.x + v4.x + v5.x;
    float sy = v0.y + v1.y + v2.y + v3.y + v4.y + v5.y;
    float sz = v0.z + v1.z + v2.z + v3.z + v4.z + v5.z;
    float sw = v0.w + v1.w + v2.w + v3.w + v4.w + v5.w;
    uint2 pt, ps;
    pt.x = (unsigned)f2bf(v0.x) | ((unsigned)f2bf(v0.y) << 16);
    pt.y = (unsigned)f2bf(v0.z) | ((unsigned)f2bf(v0.w) << 16);
    ps.x = (unsigned)f2bf(sx) | ((unsigned)f2bf(sy) << 16);
    ps.y = (unsigned)f2bf(sz) | ((unsigned)f2bf(sw) << 16);
    *(uint2*)&sA[row][4 * c] = pt;
    *(uint2*)&sA[row][128 + 4 * c] = ps;
    const float4 wa = *(const float4*)&W_att[4 * c];
    float p = v0.x * wa.x + v0.y * wa.y + v0.z * wa.z + v0.w * wa.w;
    #pragma unroll
    for (int off = 16; off; off >>= 1) p += __shfl_xor(p, off);
    if (c == 0) attT[row] = p;
  }
  __syncthreads();

  int w = tid >> 6;                        // wave 0..3 -> rows w*16..+15
  int l = tid & 63;
  int r15 = l & 15, g = l >> 4;
  int rowBase = w << 4;

  // ---- GEMM app ----
  f32x4 accA[8];
  {
    bf16x8 aF[8];
    #pragma unroll
    for (int k = 0; k < 8; ++k)
      aF[k] = *(const bf16x8*)&sA[rowBase + r15][(k << 5) + (g << 3)];
    #pragma unroll
    for (int n = 0; n < 8; ++n) {
      f32x4 acc = {0.f, 0.f, 0.f, 0.f};
      #pragma unroll
      for (int k = 0; k < 8; ++k) {
        bf16x8 bF = *(const bf16x8*)&Wt[(((size_t)(n << 4) + r15) << 8) + (k << 5) + (g << 3)];
        acc = __builtin_amdgcn_mfma_f32_16x16x32_bf16(aF[k], bF, acc, 0, 0, 0);
      }
      accA[n] = acc;
    }
  }
  __syncthreads();

  // ---- gather loc ----
  #pragma unroll 2
  for (int it = 0; it < BM / 8; ++it) {
    int row = (it << 3) + hw;
    const int* wp = walks + (size_t)(BB + b0 + row) * 6;
    int n0 = wp[0], n1 = wp[1], n2 = wp[2], n3 = wp[3], n4 = wp[4], n5 = wp[5];
    const float4 v0 = *(const float4*)&x_loc[((size_t)n0 << 7) + 4 * c];
    const float4 v1 = *(const float4*)&x_loc[((size_t)n1 << 7) + 4 * c];
    const float4 v2 = *(const float4*)&x_loc[((size_t)n2 << 7) + 4 * c];
    const float4 v3 = *(const float4*)&x_loc[((size_t)n3 << 7) + 4 * c];
    const float4 v4 = *(const float4*)&x_loc[((size_t)n4 << 7) + 4 * c];
    const float4 v5 = *(const float4*)&x_loc[((size_t)n5 << 7) + 4 * c];
    float sx = v0.x + v1.x + v2.x + v3.x + v4.x + v5.x;
    float sy = v0.y + v1.y + v2.y + v3.y + v4.y + v5.y;
    float sz = v0.z + v1.z + v2.z + v3.z + v4.z + v5.z;
    float sw = v0.w + v1.w + v2.w + v3.w + v4.w + v5.w;
    uint2 pt, ps;
    pt.x = (unsigned)f2bf(v0.x) | ((unsigned)f2bf(v0.y) << 16);
    pt.y = (unsigned)f2bf(v0.z) | ((unsigned)f2bf(v0.w) << 16);
    ps.x = (unsigned)f2bf(sx) | ((unsigned)f2bf(sy) << 16);
    ps.y = (unsigned)f2bf(sz) | ((unsigned)f2bf(sw) << 16);
    *(uint2*)&sA[row][4 * c] = pt;
    *(uint2*)&sA[row][128 + 4 * c] = ps;
  }
  __syncthreads();

  // ---- GEMM loc ----
  f32x4 accL[8];
  {
    bf16x8 aF[8];
    #pragma unroll
    for (int k = 0; k < 8; ++k)
      aF[k] = *(const bf16x8*)&sA[rowBase + r15][(k << 5) + (g << 3)];
    const unsigned short* WtL = Wt + (1 << 15);
    #pragma unroll
    for (int n = 0; n < 8; ++n) {
      f32x4 acc = {0.f, 0.f, 0.f, 0.f};
      #pragma unroll
      for (int k = 0; k < 8; ++k) {
        bf16x8 bF = *(const bf16x8*)&WtL[(((size_t)(n << 4) + r15) << 8) + (k << 5) + (g << 3)];
        acc = __builtin_amdgcn_mfma_f32_16x16x32_bf16(aF[k], bF, acc, 0, 0, 0);
      }
      accL[n] = acc;
    }
  }

  // ---- epilogue: attention ----
  float bA[8], bL[8], wv[8];
  #pragma unroll
  for (int n = 0; n < 8; ++n) {
    int col = (n << 4) + r15;
    bA[n] = b_app[col];
    bL[n] = b_loc[col];
    wv[n] = W_att[128 + col];
  }
  float batt = b_att[0];

  int trow[4];
  #pragma unroll
  for (int r = 0; r < 4; ++r) trow[r] = target[b0 + rowBase + (g << 2) + r];
  float tts[8][4];
  #pragma unroll
  for (int n = 0; n < 8; ++n)
    #pragma unroll
    for (int r = 0; r < 4; ++r)
      tts[n][r] = x_time[((size_t)trow[r] << 7) + (n << 4) + r15];

  #pragma unroll
  for (int r = 0; r < 4; ++r) {
    float fa[8], fl[8];
    float dA = 0.f, dL = 0.f, dT = 0.f;
    #pragma unroll
    for (int n = 0; n < 8; ++n) {
      fa[n] = fmaxf(accA[n][r] + bA[n], 0.f);
      fl[n] = fmaxf(accL[n][r] + bL[n], 0.f);
      dA += fa[n] * wv[n];
      dL += fl[n] * wv[n];
      dT += tts[n][r] * wv[n];
    }
    #pragma unroll
    for (int off = 1; off < 16; off <<= 1) {
      dA += __shfl_xor(dA, off);
      dL += __shfl_xor(dL, off);
      dT += __shfl_xor(dT, off);
    }
    float at = attT[rowBase + (g << 2) + r];
    float s0 = at + dA + batt;
    float s1 = at + dL + batt;
    float s2 = at + dT + batt;
    float m = fmaxf(s0, fmaxf(s1, s2));
    float e0 = expf(s0 - m), e1 = expf(s1 - m), e2 = expf(s2 - m);
    float inv = 1.f / (e0 + e1 + e2);
    size_t grow = (size_t)(b0 + rowBase + (g << 2) + r);
    #pragma unroll
    for (int n = 0; n < 8; ++n)
      out[(grow << 7) + (n << 4) + r15] = (e0 * fa[n] + e1 * fl[n] + e2 * tts[n][r]) * inv;
  }
}

extern "C" void kernel_launch(void* const* d_in, const int* in_sizes, int n_in,
                              void* d_out, int out_size, void* d_ws, size_t ws_size,
                              hipStream_t stream) {
  (void)in_sizes; (void)n_in; (void)out_size; (void)ws_size;
  const float* x_app   = (const float*)d_in[0];
  const float* x_loc   = (const float*)d_in[1];
  const float* x_time  = (const float*)d_in[2];
  const int*   neighbors = (const int*)d_in[3];
  const float* ew      = (const float*)d_in[4];
  const int*   target  = (const int*)d_in[5];
  const float* W_app   = (const float*)d_in[6];
  const float* b_app   = (const float*)d_in[7];
  const float* W_loc   = (const float*)d_in[8];
  const float* b_loc   = (const float*)d_in[9];
  const float* W_att   = (const float*)d_in[10];
  const float* b_att   = (const float*)d_in[11];
  float* out = (float*)d_out;
  int* walks = (int*)d_ws;                           // [2][BB][6] = 786 KB
  unsigned short* Wt =
      (unsigned short*)((char*)d_ws + (size_t)2 * BB * 6 * sizeof(int)); // 128 KB

  Keys keys;
  unsigned k1a, k1b, k2a, k2b;
  threefry2x32(0u, 42u, 0u, 0u, &k1a, &k1b);
  threefry2x32(0u, 42u, 0u, 1u, &k2a, &k2b);
  for (unsigned s = 0; s < 5; ++s) {
    threefry2x32(k1a, k1b, 0u, s, &keys.a[s][0], &keys.a[s][1]);
    threefry2x32(k2a, k2b, 0u, s, &keys.l[s][0], &keys.l[s][1]);
  }

  walk_kernel<<<(2 * BB * 32) / 256, 256, 0, stream>>>(neighbors, ew, target, walks, keys);
  prep_w<<<16, 256, 0, stream>>>(W_app, W_loc, Wt);
  fuse2<<<BB / BM, 256, 0, stream>>>(x_app, x_loc, x_time, target, walks, Wt,
                                     W_att, b_att, b_app, b_loc, out);
}

// Round 3
// 61.133 us; speedup vs baseline: 1.6113x; 1.0610x over previous
//
#include <hip/hip_runtime.h>
#include <stdint.h>

#define NN 200000
#define DEG 32
#define BB 16384
#define DD 128
#define HH 128
#define BM 16

typedef __attribute__((ext_vector_type(8))) short bf16x8;
typedef __attribute__((ext_vector_type(4))) float f32x4;

struct Keys { unsigned a[5][2]; unsigned l[5][2]; };

__host__ __device__ __forceinline__ unsigned rotl32(unsigned v, int r) {
  return (v << r) | (v >> (32 - r));
}

__host__ __device__ __forceinline__ void threefry2x32(
    unsigned k0, unsigned k1, unsigned x0, unsigned x1,
    unsigned* o0, unsigned* o1) {
  unsigned ks0 = k0, ks1 = k1, ks2 = k0 ^ k1 ^ 0x1BD11BDAu;
  x0 += ks0; x1 += ks1;
#define TF_RND(r) { x0 += x1; x1 = rotl32(x1, (r)); x1 ^= x0; }
  TF_RND(13) TF_RND(15) TF_RND(26) TF_RND(6)
  x0 += ks1; x1 += ks2 + 1u;
  TF_RND(17) TF_RND(29) TF_RND(16) TF_RND(24)
  x0 += ks2; x1 += ks0 + 2u;
  TF_RND(13) TF_RND(15) TF_RND(26) TF_RND(6)
  x0 += ks0; x1 += ks1 + 3u;
  TF_RND(17) TF_RND(29) TF_RND(16) TF_RND(24)
  x0 += ks1; x1 += ks2 + 4u;
  TF_RND(13) TF_RND(15) TF_RND(26) TF_RND(6)
  x0 += ks2; x1 += ks0 + 5u;
#undef TF_RND
  *o0 = x0; *o1 = x1;
}

__device__ __forceinline__ unsigned short f2bf(float x) {
  unsigned u = __float_as_uint(x);
  unsigned r = (u + 0x7fffu + ((u >> 16) & 1u)) >> 16;
  return (unsigned short)r;
}

// ---------------- walk kernel (unchanged, verified) ----------------
__global__ __launch_bounds__(256) void walk_kernel(
    const int* __restrict__ neighbors, const float* __restrict__ ew,
    const int* __restrict__ target, int* __restrict__ walks, Keys keys) {
  int lane = threadIdx.x & 63;
  int sub = lane & 31;
  int grp = (int)((blockIdx.x * 256 + threadIdx.x) >> 5);
  int wk = grp >= BB ? 1 : 0;
  int b = grp - wk * BB;

  int cur = target[b];
  if (sub == 0) walks[(size_t)grp * 6] = cur;

  const float TINY = 1.17549435e-38f;

  for (int s = 0; s < 5; ++s) {
    int nb = neighbors[(size_t)cur * DEG + sub];
    float w = ew[(size_t)cur * DEG + sub];
    unsigned j = (unsigned)b * DEG + (unsigned)sub;
    unsigned k0 = wk ? keys.l[s][0] : keys.a[s][0];
    unsigned k1 = wk ? keys.l[s][1] : keys.a[s][1];
    unsigned y0, y1;
    threefry2x32(k0, k1, 0u, j, &y0, &y1);
    unsigned bits = y0 ^ y1;
    float f = __uint_as_float((bits >> 9) | 0x3f800000u) - 1.0f;
    float u = fmaxf(TINY, f + TINY);
    float g = -logf(-logf(u));
    float v = g + logf(w);
    int idx = sub;
    #pragma unroll
    for (int off = 16; off; off >>= 1) {
      float vo = __shfl_xor(v, off);
      int io = __shfl_xor(idx, off);
      if (vo > v || (vo == v && io < idx)) { v = vo; idx = io; }
    }
    cur = __shfl(nb, (lane & 32) + idx);
    if (sub == 0) walks[(size_t)grp * 6 + s + 1] = cur;
  }
}

// ---------------- W transpose+bf16 prep: Wt[2][128 n][256 k] ----------------
__global__ __launch_bounds__(256) void prep_w(
    const float* __restrict__ Wapp, const float* __restrict__ Wloc,
    unsigned short* __restrict__ Wt) {
  int blk = blockIdx.x;                 // 16 blocks: mat(2) x kchunk(8)
  int mat = blk >> 3;
  int k0 = (blk & 7) << 5;
  const float* W = mat ? Wloc : Wapp;
  __shared__ float tile[32][129];
  int t = threadIdx.x;
  #pragma unroll
  for (int i = 0; i < 16; ++i) {
    int idx = t + (i << 8);
    int kk = idx >> 7, n = idx & 127;
    tile[kk][n] = W[((size_t)(k0 + kk) << 7) + n];
  }
  __syncthreads();
  int n = t >> 1, h = (t & 1) << 4;
  unsigned pk[8];
  #pragma unroll
  for (int j = 0; j < 8; ++j) {
    float lo = tile[h + 2 * j][n];
    float hi = tile[h + 2 * j + 1][n];
    pk[j] = (unsigned)f2bf(lo) | ((unsigned)f2bf(hi) << 16);
  }
  unsigned short* dst = Wt + ((size_t)mat << 15) + ((size_t)n << 8) + k0 + h;
  uint4 lo4; lo4.x = pk[0]; lo4.y = pk[1]; lo4.z = pk[2]; lo4.w = pk[3];
  uint4 hi4; hi4.x = pk[4]; hi4.y = pk[5]; hi4.z = pk[6]; hi4.w = pk[7];
  reinterpret_cast<uint4*>(dst)[0] = lo4;
  reinterpret_cast<uint4*>(dst)[1] = hi4;
}

// -------- fused gather + MFMA GEMM + attention, BM=16, grid=1024 --------
__global__ __launch_bounds__(256, 4) void fuse3(
    const float* __restrict__ x_app, const float* __restrict__ x_loc,
    const float* __restrict__ x_time, const int* __restrict__ target,
    const int* __restrict__ walks, const unsigned short* __restrict__ Wt,
    const float* __restrict__ W_att, const float* __restrict__ b_att,
    const float* __restrict__ b_app, const float* __restrict__ b_loc,
    float* __restrict__ out) {
  __shared__ unsigned short sA[BM][264];   // app: [t(128) | sum(128)], pad 8
  __shared__ unsigned short sL[BM][264];   // loc
  __shared__ float attT[BM];               // t_app . W_att[:128]
  __shared__ float4 sRed[4][BM];           // per-wave partial {dA,dL,dT}

  int tid = threadIdx.x;
  int b0 = blockIdx.x * BM;
  int hw = tid >> 5;                       // half-wave 0..7
  int c = tid & 31;

  // ---- both gathers issued back-to-back (max loads in flight) ----
  #pragma unroll
  for (int it = 0; it < BM / 8; ++it) {
    int row = (it << 3) + hw;
    {
      const int* wp = walks + (size_t)(b0 + row) * 6;
      int n0 = wp[0], n1 = wp[1], n2 = wp[2], n3 = wp[3], n4 = wp[4], n5 = wp[5];
      const float4 v0 = *(const float4*)&x_app[((size_t)n0 << 7) + 4 * c];
      const float4 v1 = *(const float4*)&x_app[((size_t)n1 << 7) + 4 * c];
      const float4 v2 = *(const float4*)&x_app[((size_t)n2 << 7) + 4 * c];
      const float4 v3 = *(const float4*)&x_app[((size_t)n3 << 7) + 4 * c];
      const float4 v4 = *(const float4*)&x_app[((size_t)n4 << 7) + 4 * c];
      const float4 v5 = *(const float4*)&x_app[((size_t)n5 << 7) + 4 * c];
      float sx = v0.x + v1.x + v2.x + v3.x + v4.x + v5.x;
      float sy = v0.y + v1.y + v2.y + v3.y + v4.y + v5.y;
      float sz = v0.z + v1.z + v2.z + v3.z + v4.z + v5.z;
      float sw = v0.w + v1.w + v2.w + v3.w + v4.w + v5.w;
      uint2 pt, ps;
      pt.x = (unsigned)f2bf(v0.x) | ((unsigned)f2bf(v0.y) << 16);
      pt.y = (unsigned)f2bf(v0.z) | ((unsigned)f2bf(v0.w) << 16);
      ps.x = (unsigned)f2bf(sx) | ((unsigned)f2bf(sy) << 16);
      ps.y = (unsigned)f2bf(sz) | ((unsigned)f2bf(sw) << 16);
      *(uint2*)&sA[row][4 * c] = pt;
      *(uint2*)&sA[row][128 + 4 * c] = ps;
      const float4 wa = *(const float4*)&W_att[4 * c];
      float p = v0.x * wa.x + v0.y * wa.y + v0.z * wa.z + v0.w * wa.w;
      #pragma unroll
      for (int off = 16; off; off >>= 1) p += __shfl_xor(p, off);
      if (c == 0) attT[row] = p;
    }
    {
      const int* wp = walks + (size_t)(BB + b0 + row) * 6;
      int n0 = wp[0], n1 = wp[1], n2 = wp[2], n3 = wp[3], n4 = wp[4], n5 = wp[5];
      const float4 v0 = *(const float4*)&x_loc[((size_t)n0 << 7) + 4 * c];
      const float4 v1 = *(const float4*)&x_loc[((size_t)n1 << 7) + 4 * c];
      const float4 v2 = *(const float4*)&x_loc[((size_t)n2 << 7) + 4 * c];
      const float4 v3 = *(const float4*)&x_loc[((size_t)n3 << 7) + 4 * c];
      const float4 v4 = *(const float4*)&x_loc[((size_t)n4 << 7) + 4 * c];
      const float4 v5 = *(const float4*)&x_loc[((size_t)n5 << 7) + 4 * c];
      float sx = v0.x + v1.x + v2.x + v3.x + v4.x + v5.x;
      float sy = v0.y + v1.y + v2.y + v3.y + v4.y + v5.y;
      float sz = v0.z + v1.z + v2.z + v3.z + v4.z + v5.z;
      float sw = v0.w + v1.w + v2.w + v3.w + v4.w + v5.w;
      uint2 pt, ps;
      pt.x = (unsigned)f2bf(v0.x) | ((unsigned)f2bf(v0.y) << 16);
      pt.y = (unsigned)f2bf(v0.z) | ((unsigned)f2bf(v0.w) << 16);
      ps.x = (unsigned)f2bf(sx) | ((unsigned)f2bf(sy) << 16);
      ps.y = (unsigned)f2bf(sz) | ((unsigned)f2bf(sw) << 16);
      *(uint2*)&sL[row][4 * c] = pt;
      *(uint2*)&sL[row][128 + 4 * c] = ps;
    }
  }
  __syncthreads();

  int w = tid >> 6;                        // wave 0..3 -> n-tiles {2w, 2w+1}
  int l = tid & 63;
  int r15 = l & 15, g = l >> 4;

  // ---- GEMMs: wave w computes cols 32w..32w+31 for all 16 rows ----
  f32x4 accA[2], accL[2];
  {
    bf16x8 aF[8], lF[8];
    #pragma unroll
    for (int k = 0; k < 8; ++k) {
      aF[k] = *(const bf16x8*)&sA[r15][(k << 5) + (g << 3)];
      lF[k] = *(const bf16x8*)&sL[r15][(k << 5) + (g << 3)];
    }
    #pragma unroll
    for (int n = 0; n < 2; ++n) {
      int col = ((w << 1) + n) << 4;
      f32x4 a1 = {0.f, 0.f, 0.f, 0.f}, a2 = {0.f, 0.f, 0.f, 0.f};
      #pragma unroll
      for (int k = 0; k < 8; ++k) {
        bf16x8 bA = *(const bf16x8*)&Wt[(((size_t)col + r15) << 8) + (k << 5) + (g << 3)];
        bf16x8 bL = *(const bf16x8*)&Wt[(1 << 15) + (((size_t)col + r15) << 8) + (k << 5) + (g << 3)];
        a1 = __builtin_amdgcn_mfma_f32_16x16x32_bf16(aF[k], bA, a1, 0, 0, 0);
        a2 = __builtin_amdgcn_mfma_f32_16x16x32_bf16(lF[k], bL, a2, 0, 0, 0);
      }
      accA[n] = a1;
      accL[n] = a2;
    }
  }

  // ---- epilogue ----
  float bA[2], bL[2], wv[2];
  #pragma unroll
  for (int n = 0; n < 2; ++n) {
    int col = (((w << 1) + n) << 4) + r15;
    bA[n] = b_app[col];
    bL[n] = b_loc[col];
    wv[n] = W_att[128 + col];
  }
  float batt = b_att[0];

  int trow[4];
  #pragma unroll
  for (int r = 0; r < 4; ++r) trow[r] = target[b0 + (g << 2) + r];
  float tts[2][4];
  #pragma unroll
  for (int n = 0; n < 2; ++n)
    #pragma unroll
    for (int r = 0; r < 4; ++r)
      tts[n][r] = x_time[((size_t)trow[r] << 7) + (((w << 1) + n) << 4) + r15];

  float fa[2][4], fl[2][4];
  #pragma unroll
  for (int r = 0; r < 4; ++r) {
    float dA = 0.f, dL = 0.f, dT = 0.f;
    #pragma unroll
    for (int n = 0; n < 2; ++n) {
      fa[n][r] = fmaxf(accA[n][r] + bA[n], 0.f);
      fl[n][r] = fmaxf(accL[n][r] + bL[n], 0.f);
      dA += fa[n][r] * wv[n];
      dL += fl[n][r] * wv[n];
      dT += tts[n][r] * wv[n];
    }
    #pragma unroll
    for (int off = 1; off < 16; off <<= 1) {
      dA += __shfl_xor(dA, off);
      dL += __shfl_xor(dL, off);
      dT += __shfl_xor(dT, off);
    }
    if (r15 == 0) {
      float4 q; q.x = dA; q.y = dL; q.z = dT; q.w = 0.f;
      sRed[w][(g << 2) + r] = q;
    }
  }
  __syncthreads();

  #pragma unroll
  for (int r = 0; r < 4; ++r) {
    int row = (g << 2) + r;
    float4 q0 = sRed[0][row], q1 = sRed[1][row], q2 = sRed[2][row], q3 = sRed[3][row];
    float at = attT[row] + batt;
    float s0 = at + q0.x + q1.x + q2.x + q3.x;
    float s1 = at + q0.y + q1.y + q2.y + q3.y;
    float s2 = at + q0.z + q1.z + q2.z + q3.z;
    float m = fmaxf(s0, fmaxf(s1, s2));
    float e0 = expf(s0 - m), e1 = expf(s1 - m), e2 = expf(s2 - m);
    float inv = 1.f / (e0 + e1 + e2);
    size_t grow = (size_t)(b0 + row);
    #pragma unroll
    for (int n = 0; n < 2; ++n) {
      int col = (((w << 1) + n) << 4) + r15;
      out[(grow << 7) + col] = (e0 * fa[n][r] + e1 * fl[n][r] + e2 * tts[n][r]) * inv;
    }
  }
}

extern "C" void kernel_launch(void* const* d_in, const int* in_sizes, int n_in,
                              void* d_out, int out_size, void* d_ws, size_t ws_size,
                              hipStream_t stream) {
  (void)in_sizes; (void)n_in; (void)out_size; (void)ws_size;
  const float* x_app   = (const float*)d_in[0];
  const float* x_loc   = (const float*)d_in[1];
  const float* x_time  = (const float*)d_in[2];
  const int*   neighbors = (const int*)d_in[3];
  const float* ew      = (const float*)d_in[4];
  const int*   target  = (const int*)d_in[5];
  const float* W_app   = (const float*)d_in[6];
  const float* b_app   = (const float*)d_in[7];
  const float* W_loc   = (const float*)d_in[8];
  const float* b_loc   = (const float*)d_in[9];
  const float* W_att   = (const float*)d_in[10];
  const float* b_att   = (const float*)d_in[11];
  float* out = (float*)d_out;
  int* walks = (int*)d_ws;                           // [2][BB][6] = 786 KB
  unsigned short* Wt =
      (unsigned short*)((char*)d_ws + (size_t)2 * BB * 6 * sizeof(int)); // 128 KB

  Keys keys;
  unsigned k1a, k1b, k2a, k2b;
  threefry2x32(0u, 42u, 0u, 0u, &k1a, &k1b);
  threefry2x32(0u, 42u, 0u, 1u, &k2a, &k2b);
  for (unsigned s = 0; s < 5; ++s) {
    threefry2x32(k1a, k1b, 0u, s, &keys.a[s][0], &keys.a[s][1]);
    threefry2x32(k2a, k2b, 0u, s, &keys.l[s][0], &keys.l[s][1]);
  }

  walk_kernel<<<(2 * BB * 32) / 256, 256, 0, stream>>>(neighbors, ew, target, walks, keys);
  prep_w<<<16, 256, 0, stream>>>(W_app, W_loc, Wt);
  fuse3<<<BB / BM, 256, 0, stream>>>(x_app, x_loc, x_time, target, walks, Wt,
                                     W_att, b_att, b_app, b_loc, out);
}